// Round 1
// 4245.430 us; speedup vs baseline: 2.1505x; 2.1505x over previous
//
#include <hip/hip_runtime.h>
#include <hip/hip_bf16.h>
#include <math.h>

typedef __hip_bfloat16 bf16;
__device__ __forceinline__ float b2f(bf16 v){ return __bfloat162float(v); }
__device__ __forceinline__ bf16  f2b(float v){ return __float2bfloat16(v); }
__device__ __forceinline__ float LD(const bf16* p, size_t i){ return b2f(p[i]); }
__device__ __forceinline__ float LD(const float* p, size_t i){ return p[i]; }

#define BL 2048
#define QH 384
#define PH 288

// z LDS row stride in bf16 (odd dword stride 37 -> conflict-free for stride-74 row access)
#define ZST 74

// ---------- dtype sniff: rot rows are orthonormal (QR) ----------
__global__ void k_sniff(const void* rot, int* flag) {
    if (threadIdx.x == 0 && blockIdx.x == 0) {
        const bf16*  pb = (const bf16*)rot;
        const float* pf = (const float*)rot;
        float eb = 0.f, ef = 0.f;
        for (int r = 0; r < 8; r++) {
            float sb = 0.f, sf = 0.f;
            for (int c = 0; c < 3; c++) {
                float vb = b2f(pb[r * 9 + c]);
                float vf = pf[r * 9 + c];
                sb += vb * vb; sf += vf * vf;
            }
            eb += fabsf(sb - 1.f); ef += fabsf(sf - 1.f);
        }
        int okb = (eb < 0.5f) ? 1 : 0;   // NaN-safe
        int okf = (ef < 0.5f) ? 1 : 0;
        flag[0] = (okf && !okb) ? 0 : 1; // default bf16
    }
}

// ---------- init ----------
__global__ void k_init(const void* rf, float* __restrict__ x, const int* __restrict__ flag) {
    int i = blockIdx.x * 256 + threadIdx.x;
    if (*flag) x[i] = b2f(((const bf16*)rf)[i]);
    else       x[i] = ((const float*)rf)[i];
}

// ---------- projections + frame transform ----------
// NOTE: k and kp are written TRANSPOSED per batch: k_t[b][col(384)][j(256)],
//       kp_t[b][col(288)][j(256)] so the attention logits loop reads them
//       coalesced across lanes. q, v, qpg, vpg stay row-major.
template<typename T>
__device__ void proj_body(int row, int tid, int l, float* sm,
    const float* __restrict__ x,
    const T* Wq, const T* Wk, const T* Wv,
    const T* Wqp, const T* Wkp, const T* Wvp,
    const T* rot, const T* pos,
    bf16* q, bf16* k, bf16* v, bf16* qpg, bf16* kpg, bf16* vpg)
{
    const size_t o384 = (size_t)l * 128 * 384, o288 = (size_t)l * 128 * 288;
    float* xr = sm;           // 128
    float* ob = sm + 128;     // 2016
    float* Rm = sm + 2144;    // 9
    float* tv = sm + 2153;    // 3

    if (tid < 128)          xr[tid]       = x[(size_t)row * 128 + tid];
    else if (tid < 137)     Rm[tid - 128] = LD(rot, (size_t)row * 9 + (tid - 128));
    else if (tid < 140)     tv[tid - 137] = LD(pos, (size_t)row * 3 + (tid - 137));
    __syncthreads();

    for (int c = tid; c < 2016; c += 256) {
        const T* W; int col, wc; size_t wo;
        if (c < 1152) { int seg = c / 384; col = c - seg * 384; wc = 384; wo = o384;
                        W = (seg == 0) ? Wq : (seg == 1 ? Wk : Wv); }
        else          { int seg = (c - 1152) / 288; col = (c - 1152) - seg * 288; wc = 288; wo = o288;
                        W = (seg == 0) ? Wqp : (seg == 1 ? Wkp : Wvp); }
        float acc = 0.f;
        #pragma unroll 8
        for (int kk = 0; kk < 128; kk++) acc += xr[kk] * LD(W, wo + (size_t)kk * wc + col);
        ob[c] = acc;
    }
    __syncthreads();

    const int bb = row >> 8, ii = row & 255;

    for (int i2 = tid; i2 < 1152; i2 += 256) {
        bf16 val = f2b(ob[i2]);
        if (i2 < 384)      q[(size_t)row * 384 + i2]                          = val;
        else if (i2 < 768) k[(size_t)bb * 98304 + (size_t)(i2 - 384) * 256 + ii] = val;  // transposed
        else               v[(size_t)row * 384 + (i2 - 768)]                  = val;
    }
    for (int pt = tid; pt < 288; pt += 256) {
        int ty = pt / 96; int ip = pt - ty * 96; int base = 1152 + ty * 288 + ip * 3;
        float p0 = ob[base], p1 = ob[base + 1], p2 = ob[base + 2];
        float g0 = Rm[0] * p0 + Rm[1] * p1 + Rm[2] * p2 + tv[0];
        float g1 = Rm[3] * p0 + Rm[4] * p1 + Rm[5] * p2 + tv[1];
        float g2 = Rm[6] * p0 + Rm[7] * p1 + Rm[8] * p2 + tv[2];
        if (ty == 0) {
            qpg[(size_t)row * 288 + ip * 3 + 0] = f2b(g0);
            qpg[(size_t)row * 288 + ip * 3 + 1] = f2b(g1);
            qpg[(size_t)row * 288 + ip * 3 + 2] = f2b(g2);
        } else if (ty == 1) {  // transposed
            kpg[(size_t)bb * 73728 + (size_t)(ip * 3 + 0) * 256 + ii] = f2b(g0);
            kpg[(size_t)bb * 73728 + (size_t)(ip * 3 + 1) * 256 + ii] = f2b(g1);
            kpg[(size_t)bb * 73728 + (size_t)(ip * 3 + 2) * 256 + ii] = f2b(g2);
        } else {
            vpg[(size_t)row * 288 + ip * 3 + 0] = f2b(g0);
            vpg[(size_t)row * 288 + ip * 3 + 1] = f2b(g1);
            vpg[(size_t)row * 288 + ip * 3 + 2] = f2b(g2);
        }
    }
}

__global__ __launch_bounds__(256) void k_proj(
    const float* __restrict__ x,
    const void* Wq, const void* Wk, const void* Wv,
    const void* Wqp, const void* Wkp, const void* Wvp,
    const void* rot, const void* pos,
    bf16* q, bf16* k, bf16* v, bf16* qpg, bf16* kpg, bf16* vpg,
    const int* __restrict__ flag, int l)
{
    extern __shared__ float smp[];
    int row = blockIdx.x, tid = threadIdx.x;
    if (*flag) proj_body<bf16>(row, tid, l, smp, x,
        (const bf16*)Wq, (const bf16*)Wk, (const bf16*)Wv,
        (const bf16*)Wqp, (const bf16*)Wkp, (const bf16*)Wvp,
        (const bf16*)rot, (const bf16*)pos, q, k, v, qpg, kpg, vpg);
    else proj_body<float>(row, tid, l, smp, x,
        (const float*)Wq, (const float*)Wk, (const float*)Wv,
        (const float*)Wqp, (const float*)Wkp, (const float*)Wvp,
        (const float*)rot, (const float*)pos, q, k, v, qpg, kpg, vpg);
}

// ---------- fused attention + Wo + LN1 + MLP + LN2 ----------
template<typename T>
__device__ void attn_body(int row, int tid, int l, char* smc,
    const bf16* q, const bf16* k, const bf16* v,
    const bf16* qpg, const bf16* kpg, const bf16* vpg,
    const T* z, const T* Wpb, const T* coef, const T* rot, const T* pos,
    float* __restrict__ x,
    const T* Wo, const T* bo, const T* g1, const T* b1ln,
    const T* w1, const T* bb1, const T* w2, const T* bb2,
    const T* w3, const T* bb3, const T* g2, const T* b2ln)
{
    const size_t oWpb = (size_t)l * 768, oCo = (size_t)l * 12;
    const size_t oWo = (size_t)l * 1824 * 128, oB = (size_t)l * 128, oM = (size_t)l * 128 * 128;

    bf16*  zb  = (bf16*)smc;              // 256 rows, stride ZST(74) bf16 = 37888 B
    float* fsm = (float*)(smc + 37888);
    float (*al)[256] = (float(*)[256])(fsm);
    float* fr   = fsm + 3072;
    float* qi   = fsm + 4896;
    float* qpi  = fsm + 5280;
    float* wpb  = fsm + 5568;
    float* chv  = fsm + 6336;
    float* Rm   = fsm + 6348;
    float* tv   = fsm + 6357;
    float (*red)[8] = (float(*)[8])(fsm + 6360);
    float* red2 = fsm + 6456;

    int b = row >> 8;

    if constexpr (sizeof(T) == 2) {
        // global z row = 64 bf16 (32 dwords) per j; LDS stride = 37 dwords (odd -> no conflicts)
        const uint* zr = reinterpret_cast<const uint*>((const bf16*)z + (size_t)row * 16384);
        uint* zb32 = reinterpret_cast<uint*>(zb);
        for (int u = tid; u < 8192; u += 256) { int r = u >> 5, c = u & 31; zb32[r * 37 + c] = zr[u]; }
    } else {
        const float* zr = (const float*)z + (size_t)row * 16384;
        for (int u = tid; u < 16384; u += 256) { int r = u >> 6, c = u & 63; zb[r * ZST + c] = f2b(zr[u]); }
    }
    for (int c2 = tid; c2 < 384; c2 += 256) qi[c2]  = b2f(q[(size_t)row * 384 + c2]);
    for (int c2 = tid; c2 < 288; c2 += 256) qpi[c2] = b2f(qpg[(size_t)row * 288 + c2]);
    for (int c2 = tid; c2 < 768; c2 += 256) wpb[c2] = LD(Wpb, oWpb + c2);
    if (tid < 12) { float cc = LD(coef, oCo + tid); chv[tid] = -log1pf(expf(cc)) * (1.f / 12.f); }
    else if (tid >= 16 && tid < 25) Rm[tid - 16] = LD(rot, (size_t)row * 9 + (tid - 16));
    else if (tid >= 25 && tid < 28) tv[tid - 25] = LD(pos, (size_t)row * 3 + (tid - 25));
    __syncthreads();

    const int j = tid;
    float lg[12];
    #pragma unroll
    for (int h = 0; h < 12; h++) lg[h] = 0.f;

    #pragma unroll 4
    for (int d = 0; d < 64; d++) {
        float zv = b2f(zb[j * ZST + d]);
        #pragma unroll
        for (int h = 0; h < 12; h++) lg[h] += zv * wpb[d * 12 + h];
    }

    // transposed K / KP reads: lane j reads column j -> coalesced across lanes
    const bf16* kt  = k   + (size_t)b * 98304 + j;
    const bf16* kpt = kpg + (size_t)b * 73728 + j;
    #pragma unroll 2
    for (int h = 0; h < 12; h++) {
        float nd = 0.f;
        #pragma unroll
        for (int d = 0; d < 32; d++)
            nd += qi[h * 32 + d] * b2f(kt[(size_t)(h * 32 + d) * 256]);
        float qk = 0.f, kp2h = 0.f, qp2h = 0.f;
        #pragma unroll
        for (int m = 0; m < 24; m++) {
            float qv = qpi[h * 24 + m], kv = b2f(kpt[(size_t)(h * 24 + m) * 256]);
            qk += qv * kv; kp2h += kv * kv; qp2h += qv * qv;
        }
        float sp = chv[h] * (qp2h + kp2h - 2.f * qk);
        lg[h] = (lg[h] + nd * 0.17677669529663687f + sp) * 0.5773502691896258f;
    }

    int w = tid >> 6;
    #pragma unroll
    for (int h = 0; h < 12; h++) {
        float vv = lg[h];
        for (int off = 32; off; off >>= 1) vv = fmaxf(vv, __shfl_xor(vv, off, 64));
        if ((tid & 63) == 0) red[h][w] = vv;
    }
    __syncthreads();
    float mh[12];
    #pragma unroll
    for (int h = 0; h < 12; h++)
        mh[h] = fmaxf(fmaxf(red[h][0], red[h][1]), fmaxf(red[h][2], red[h][3]));
    #pragma unroll
    for (int h = 0; h < 12; h++) {
        float e = expf(lg[h] - mh[h]); lg[h] = e;
        float ss = e;
        for (int off = 32; off; off >>= 1) ss += __shfl_xor(ss, off, 64);
        if ((tid & 63) == 0) red[h][4 + w] = ss;
    }
    __syncthreads();
    #pragma unroll
    for (int h = 0; h < 12; h++) {
        float S = red[h][4] + red[h][5] + red[h][6] + red[h][7];
        al[h][j] = lg[h] / S;
    }
    __syncthreads();

    for (int o = tid; o < 1440; o += 256) {
        float acc = 0.f;
        if (o < 384) {
            int h = o >> 5;
            const bf16* vb = v + (size_t)b * 256 * 384 + o;
            for (int jj = 0; jj < 256; jj++) acc += al[h][jj] * b2f(vb[(size_t)jj * 384]);
            fr[o] = acc;
        } else if (o < 1152) {
            int oo = o - 384; int h = oo >> 6, d = oo & 63;
            for (int jj = 0; jj < 256; jj++) acc += al[h][jj] * b2f(zb[jj * ZST + d]);
            fr[o] = acc;
        } else {
            int o3 = o - 1152; int h = o3 / 24;
            const bf16* vpb = vpg + (size_t)b * 256 * 288 + o3;
            for (int jj = 0; jj < 256; jj++) acc += al[h][jj] * b2f(vpb[(size_t)jj * 288]);
            qpi[o3] = acc;
        }
    }
    __syncthreads();

    if (tid < 96) {
        int t3 = tid * 3;
        float u0 = qpi[t3 + 0] - tv[0], u1 = qpi[t3 + 1] - tv[1], u2 = qpi[t3 + 2] - tv[2];
        float f0 = Rm[0] * u0 + Rm[3] * u1 + Rm[6] * u2;
        float f1 = Rm[1] * u0 + Rm[4] * u1 + Rm[7] * u2;
        float f2 = Rm[2] * u0 + Rm[5] * u1 + Rm[8] * u2;
        float fd = sqrtf(f0 * f0 + f1 * f1 + f2 * f2);
        float inv = 1.f / (fd + 1e-4f);
        fr[1152 + t3 + 0] = f0; fr[1152 + t3 + 1] = f1; fr[1152 + t3 + 2] = f2;
        fr[1440 + tid] = fd;
        fr[1536 + t3 + 0] = f0 * inv; fr[1536 + t3 + 1] = f1 * inv; fr[1536 + t3 + 2] = f2 * inv;
    }
    __syncthreads();

    float* pacc = fsm;
    float* shx  = fsm + 256;
    int col = tid & 127, half = tid >> 7;

    float acc = 0.f;
    #pragma unroll 8
    for (int kk = half * 912; kk < half * 912 + 912; kk++)
        acc += fr[kk] * LD(Wo, oWo + (size_t)kk * 128 + col);
    pacc[tid] = acc;
    __syncthreads();

    auto bsum = [&](float vv) -> float {
        for (int off = 32; off; off >>= 1) vv += __shfl_xor(vv, off, 64);
        if ((tid & 63) == 0) red2[tid >> 6] = vv;
        __syncthreads();
        float s = red2[0] + red2[1] + red2[2] + red2[3];
        __syncthreads();
        return s;
    };

    float val = x[(size_t)row * 128 + col] + LD(bo, oB + col) + pacc[col] + pacc[128 + col];

    float mean = bsum(val) * (1.f / 256.f);
    float dv = val - mean;
    float var = bsum(dv * dv) * (1.f / 256.f);
    float xl = dv * rsqrtf(var + 1e-5f) * LD(g1, oB + col) + LD(b1ln, oB + col);
    shx[col] = xl;
    __syncthreads();

    float a1 = LD(bb1, oB + col);
    #pragma unroll 8
    for (int kk = 0; kk < 128; kk++) a1 += shx[kk] * LD(w1, oM + kk * 128 + col);
    a1 = fmaxf(a1, 0.f);
    __syncthreads();
    shx[col] = a1;
    __syncthreads();

    float a2 = LD(bb2, oB + col);
    #pragma unroll 8
    for (int kk = 0; kk < 128; kk++) a2 += shx[kk] * LD(w2, oM + kk * 128 + col);
    a2 = fmaxf(a2, 0.f);
    __syncthreads();
    shx[col] = a2;
    __syncthreads();

    float a3 = LD(bb3, oB + col);
    #pragma unroll 8
    for (int kk = 0; kk < 128; kk++) a3 += shx[kk] * LD(w3, oM + kk * 128 + col);
    float val2 = xl + a3;

    float mean2 = bsum(val2) * (1.f / 256.f);
    float dv2 = val2 - mean2;
    float var2 = bsum(dv2 * dv2) * (1.f / 256.f);
    if (tid < 128)
        x[(size_t)row * 128 + col] = dv2 * rsqrtf(var2 + 1e-5f) * LD(g2, oB + col) + LD(b2ln, oB + col);
}

__global__ __launch_bounds__(256) void k_attn_post(
    const bf16* q, const bf16* k, const bf16* v,
    const bf16* qpg, const bf16* kpg, const bf16* vpg,
    const void* z, const void* Wpb, const void* coef, const void* rot, const void* pos,
    float* x,
    const void* Wo, const void* bo, const void* g1, const void* b1ln,
    const void* w1, const void* bb1, const void* w2, const void* bb2,
    const void* w3, const void* bb3, const void* g2, const void* b2ln,
    const int* __restrict__ flag, int l)
{
    extern __shared__ char smc[];
    int row = blockIdx.x, tid = threadIdx.x;
    if (*flag) attn_body<bf16>(row, tid, l, smc, q, k, v, qpg, kpg, vpg,
        (const bf16*)z, (const bf16*)Wpb, (const bf16*)coef, (const bf16*)rot, (const bf16*)pos, x,
        (const bf16*)Wo, (const bf16*)bo, (const bf16*)g1, (const bf16*)b1ln,
        (const bf16*)w1, (const bf16*)bb1, (const bf16*)w2, (const bf16*)bb2,
        (const bf16*)w3, (const bf16*)bb3, (const bf16*)g2, (const bf16*)b2ln);
    else attn_body<float>(row, tid, l, smc, q, k, v, qpg, kpg, vpg,
        (const float*)z, (const float*)Wpb, (const float*)coef, (const float*)rot, (const float*)pos, x,
        (const float*)Wo, (const float*)bo, (const float*)g1, (const float*)b1ln,
        (const float*)w1, (const float*)bb1, (const float*)w2, (const float*)bb2,
        (const float*)w3, (const float*)bb3, (const float*)g2, (const float*)b2ln);
}

// ---------- regression head ----------
__global__ void k_final(const float* __restrict__ x, const void* Wreg, const void* breg,
                        void* out, const int* __restrict__ flag)
{
    int idx = blockIdx.x * 256 + threadIdx.x;
    int isBF = *flag;
    int b = idx >> 7, r = (idx >> 2) & 31, c = idx & 3;
    const float* xr = x + ((size_t)(b * 256 + 224 + r)) * 128;
    if (isBF) {
        const bf16* W = (const bf16*)Wreg;
        float acc = b2f(((const bf16*)breg)[c]);
        for (int kk = 0; kk < 128; kk++) acc += xr[kk] * b2f(W[kk * 4 + c]);
        ((bf16*)out)[idx] = f2b(acc);
    } else {
        const float* W = (const float*)Wreg;
        float acc = ((const float*)breg)[c];
        for (int kk = 0; kk < 128; kk++) acc += xr[kk] * W[kk * 4 + c];
        ((float*)out)[idx] = acc;
    }
}

extern "C" void kernel_launch(void* const* d_in, const int* in_sizes, int n_in,
                              void* d_out, int out_size, void* d_ws, size_t ws_size,
                              hipStream_t stream)
{
    const void* rot  = d_in[0];
    const void* pos  = d_in[1];
    const void* resf = d_in[2];
    const void* pair = d_in[3];
    const void* Wq   = d_in[5];
    const void* Wk   = d_in[6];
    const void* Wv   = d_in[7];
    const void* Wpb  = d_in[8];
    const void* coef = d_in[9];
    const void* Wqp  = d_in[10];
    const void* Wkp  = d_in[11];
    const void* Wvp  = d_in[12];
    const void* Wo   = d_in[13];
    const void* bo   = d_in[14];
    const void* ln1g = d_in[15];
    const void* ln1b = d_in[16];
    const void* w1   = d_in[17];
    const void* b1   = d_in[18];
    const void* w2   = d_in[19];
    const void* b2   = d_in[20];
    const void* w3   = d_in[21];
    const void* b3   = d_in[22];
    const void* ln2g = d_in[23];
    const void* ln2b = d_in[24];
    const void* Wreg = d_in[25];
    const void* breg = d_in[26];

    int*   flag = (int*)d_ws;
    float* X    = (float*)d_ws + 16;
    bf16*  Qb   = (bf16*)(X + (size_t)BL * 128);
    bf16*  Kb   = Qb   + (size_t)BL * QH;
    bf16*  Vb   = Kb   + (size_t)BL * QH;
    bf16*  QPGb = Vb   + (size_t)BL * QH;
    bf16*  KPGb = QPGb + (size_t)BL * PH;
    bf16*  VPGb = KPGb + (size_t)BL * PH;

    const size_t SM_PROJ = 2156 * sizeof(float);
    const size_t SM_ATTN = 37888 + 6460 * sizeof(float);   // 63728 B

    k_sniff<<<1, 64, 0, stream>>>(rot, flag);
    k_init<<<BL * 128 / 256, 256, 0, stream>>>(resf, X, flag);

    for (int l = 0; l < 6; l++) {
        k_proj<<<BL, 256, SM_PROJ, stream>>>(
            X, Wq, Wk, Wv, Wqp, Wkp, Wvp, rot, pos,
            Qb, Kb, Vb, QPGb, KPGb, VPGb, flag, l);
        k_attn_post<<<BL, 256, SM_ATTN, stream>>>(
            Qb, Kb, Vb, QPGb, KPGb, VPGb,
            pair, Wpb, coef, rot, pos, X,
            Wo, bo, ln1g, ln1b, w1, b1, w2, b2, w3, b3, ln2g, ln2b, flag, l);
    }

    k_final<<<4, 256, 0, stream>>>(X, Wreg, breg, d_out, flag);
}

// Round 2
// 3323.823 us; speedup vs baseline: 2.7468x; 1.2773x over previous
//
#include <hip/hip_runtime.h>
#include <hip/hip_bf16.h>
#include <math.h>

typedef __hip_bfloat16 bf16;
__device__ __forceinline__ float b2f(bf16 v){ return __bfloat162float(v); }
__device__ __forceinline__ bf16  f2b(float v){ return __float2bfloat16(v); }
__device__ __forceinline__ float LD(const bf16* p, size_t i){ return b2f(p[i]); }
__device__ __forceinline__ float LD(const float* p, size_t i){ return p[i]; }

#define BL 2048
#define QH 384
#define PH 288

// ---------- dtype sniff: rot rows are orthonormal (QR) ----------
__global__ void k_sniff(const void* rot, int* flag) {
    if (threadIdx.x == 0 && blockIdx.x == 0) {
        const bf16*  pb = (const bf16*)rot;
        const float* pf = (const float*)rot;
        float eb = 0.f, ef = 0.f;
        for (int r = 0; r < 8; r++) {
            float sb = 0.f, sf = 0.f;
            for (int c = 0; c < 3; c++) {
                float vb = b2f(pb[r * 9 + c]);
                float vf = pf[r * 9 + c];
                sb += vb * vb; sf += vf * vf;
            }
            eb += fabsf(sb - 1.f); ef += fabsf(sf - 1.f);
        }
        int okb = (eb < 0.5f) ? 1 : 0;   // NaN-safe
        int okf = (ef < 0.5f) ? 1 : 0;
        flag[0] = (okf && !okb) ? 0 : 1; // default bf16
    }
}

// ---------- init ----------
__global__ void k_init(const void* rf, float* __restrict__ x, const int* __restrict__ flag) {
    int i = blockIdx.x * 256 + threadIdx.x;
    if (*flag) x[i] = b2f(((const bf16*)rf)[i]);
    else       x[i] = ((const float*)rf)[i];
}

// ---------- projections + frame transform ----------
// k and kp are written TRANSPOSED per batch: k_t[b][col(384)][j(256)],
// kp_t[b][col(288)][j(256)] so attention logits reads are lane-coalesced.
template<typename T>
__device__ void proj_body(int row, int tid, int l, float* sm,
    const float* __restrict__ x,
    const T* Wq, const T* Wk, const T* Wv,
    const T* Wqp, const T* Wkp, const T* Wvp,
    const T* rot, const T* pos,
    bf16* q, bf16* k, bf16* v, bf16* qpg, bf16* kpg, bf16* vpg)
{
    const size_t o384 = (size_t)l * 128 * 384, o288 = (size_t)l * 128 * 288;
    float* xr = sm;           // 128
    float* ob = sm + 128;     // 2016
    float* Rm = sm + 2144;    // 9
    float* tv = sm + 2153;    // 3

    if (tid < 128)          xr[tid]       = x[(size_t)row * 128 + tid];
    else if (tid < 137)     Rm[tid - 128] = LD(rot, (size_t)row * 9 + (tid - 128));
    else if (tid < 140)     tv[tid - 137] = LD(pos, (size_t)row * 3 + (tid - 137));
    __syncthreads();

    for (int c = tid; c < 2016; c += 256) {
        const T* W; int col, wc; size_t wo;
        if (c < 1152) { int seg = c / 384; col = c - seg * 384; wc = 384; wo = o384;
                        W = (seg == 0) ? Wq : (seg == 1 ? Wk : Wv); }
        else          { int seg = (c - 1152) / 288; col = (c - 1152) - seg * 288; wc = 288; wo = o288;
                        W = (seg == 0) ? Wqp : (seg == 1 ? Wkp : Wvp); }
        float acc = 0.f;
        #pragma unroll 8
        for (int kk = 0; kk < 128; kk++) acc += xr[kk] * LD(W, wo + (size_t)kk * wc + col);
        ob[c] = acc;
    }
    __syncthreads();

    const int bb = row >> 8, ii = row & 255;

    for (int i2 = tid; i2 < 1152; i2 += 256) {
        bf16 val = f2b(ob[i2]);
        if (i2 < 384)      q[(size_t)row * 384 + i2]                          = val;
        else if (i2 < 768) k[(size_t)bb * 98304 + (size_t)(i2 - 384) * 256 + ii] = val;  // transposed
        else               v[(size_t)row * 384 + (i2 - 768)]                  = val;
    }
    for (int pt = tid; pt < 288; pt += 256) {
        int ty = pt / 96; int ip = pt - ty * 96; int base = 1152 + ty * 288 + ip * 3;
        float p0 = ob[base], p1 = ob[base + 1], p2 = ob[base + 2];
        float g0 = Rm[0] * p0 + Rm[1] * p1 + Rm[2] * p2 + tv[0];
        float g1 = Rm[3] * p0 + Rm[4] * p1 + Rm[5] * p2 + tv[1];
        float g2 = Rm[6] * p0 + Rm[7] * p1 + Rm[8] * p2 + tv[2];
        if (ty == 0) {
            qpg[(size_t)row * 288 + ip * 3 + 0] = f2b(g0);
            qpg[(size_t)row * 288 + ip * 3 + 1] = f2b(g1);
            qpg[(size_t)row * 288 + ip * 3 + 2] = f2b(g2);
        } else if (ty == 1) {  // transposed
            kpg[(size_t)bb * 73728 + (size_t)(ip * 3 + 0) * 256 + ii] = f2b(g0);
            kpg[(size_t)bb * 73728 + (size_t)(ip * 3 + 1) * 256 + ii] = f2b(g1);
            kpg[(size_t)bb * 73728 + (size_t)(ip * 3 + 2) * 256 + ii] = f2b(g2);
        } else {
            vpg[(size_t)row * 288 + ip * 3 + 0] = f2b(g0);
            vpg[(size_t)row * 288 + ip * 3 + 1] = f2b(g1);
            vpg[(size_t)row * 288 + ip * 3 + 2] = f2b(g2);
        }
    }
}

__global__ __launch_bounds__(256) void k_proj(
    const float* __restrict__ x,
    const void* Wq, const void* Wk, const void* Wv,
    const void* Wqp, const void* Wkp, const void* Wvp,
    const void* rot, const void* pos,
    bf16* q, bf16* k, bf16* v, bf16* qpg, bf16* kpg, bf16* vpg,
    const int* __restrict__ flag, int l)
{
    extern __shared__ float smp[];
    int row = blockIdx.x, tid = threadIdx.x;
    if (*flag) proj_body<bf16>(row, tid, l, smp, x,
        (const bf16*)Wq, (const bf16*)Wk, (const bf16*)Wv,
        (const bf16*)Wqp, (const bf16*)Wkp, (const bf16*)Wvp,
        (const bf16*)rot, (const bf16*)pos, q, k, v, qpg, kpg, vpg);
    else proj_body<float>(row, tid, l, smp, x,
        (const float*)Wq, (const float*)Wk, (const float*)Wv,
        (const float*)Wqp, (const float*)Wkp, (const float*)Wvp,
        (const float*)rot, (const float*)pos, q, k, v, qpg, kpg, vpg);
}

// ---------- fused attention + Wo + LN1 + MLP + LN2 ----------
// z is NOT staged in LDS: logits-pair uses per-lane vector loads (L3-resident),
// feat_pair aggregation uses lane-coalesced reads (L1/L2-resident row).
// LDS = 25.8 KB -> 6 blocks/CU (24 waves) instead of 2 (8 waves).
template<typename T>
__device__ void attn_body(int row, int tid, int l, char* smc,
    const bf16* q, const bf16* k, const bf16* v,
    const bf16* qpg, const bf16* kpg, const bf16* vpg,
    const T* z, const T* Wpb, const T* coef, const T* rot, const T* pos,
    float* __restrict__ x,
    const T* Wo, const T* bo, const T* g1, const T* b1ln,
    const T* w1, const T* bb1, const T* w2, const T* bb2,
    const T* w3, const T* bb3, const T* g2, const T* b2ln)
{
    const size_t oWpb = (size_t)l * 768, oCo = (size_t)l * 12;
    const size_t oWo = (size_t)l * 1824 * 128, oB = (size_t)l * 128, oM = (size_t)l * 128 * 128;

    float* fsm = (float*)smc;
    float (*al)[256] = (float(*)[256])(fsm);      // 3072
    float* fr   = fsm + 3072;                     // 1824
    float* qi   = fsm + 4896;                     // 384
    float* qpi  = fsm + 5280;                     // 288
    float* wpb  = fsm + 5568;                     // 768
    float* chv  = fsm + 6336;                     // 12
    float* Rm   = fsm + 6348;                     // 9
    float* tv   = fsm + 6357;                     // 3
    float (*red)[8] = (float(*)[8])(fsm + 6360);  // 96
    float* red2 = fsm + 6456;                     // 4

    int b = row >> 8;

    for (int c2 = tid; c2 < 384; c2 += 256) qi[c2]  = b2f(q[(size_t)row * 384 + c2]);
    for (int c2 = tid; c2 < 288; c2 += 256) qpi[c2] = b2f(qpg[(size_t)row * 288 + c2]);
    for (int c2 = tid; c2 < 768; c2 += 256) wpb[c2] = LD(Wpb, oWpb + c2);
    if (tid < 12) { float cc = LD(coef, oCo + tid); chv[tid] = -log1pf(expf(cc)) * (1.f / 12.f); }
    else if (tid >= 16 && tid < 25) Rm[tid - 16] = LD(rot, (size_t)row * 9 + (tid - 16));
    else if (tid >= 25 && tid < 28) tv[tid - 25] = LD(pos, (size_t)row * 3 + (tid - 25));
    __syncthreads();

    const int j = tid;
    float lg[12];
    #pragma unroll
    for (int h = 0; h < 12; h++) lg[h] = 0.f;

    // logits_pair: lane j consumes z[row][j][0..63] via vector loads
    if constexpr (sizeof(T) == 2) {
        const uint4* zr4 = reinterpret_cast<const uint4*>(z + (size_t)row * 16384 + (size_t)j * 64);
        #pragma unroll
        for (int u = 0; u < 8; u++) {
            uint4 pk = zr4[u];
            union { uint4 q4; bf16 h8[8]; } cvt; cvt.q4 = pk;
            #pragma unroll
            for (int dd = 0; dd < 8; dd++) {
                float zv = b2f(cvt.h8[dd]);
                const int d = u * 8 + dd;
                #pragma unroll
                for (int h = 0; h < 12; h++) lg[h] += zv * wpb[d * 12 + h];
            }
        }
    } else {
        const float4* zr4 = reinterpret_cast<const float4*>(z + (size_t)row * 16384 + (size_t)j * 64);
        #pragma unroll
        for (int u = 0; u < 16; u++) {
            float4 pk = zr4[u];
            float zz[4] = {pk.x, pk.y, pk.z, pk.w};
            #pragma unroll
            for (int dd = 0; dd < 4; dd++) {
                float zv = zz[dd];
                const int d = u * 4 + dd;
                #pragma unroll
                for (int h = 0; h < 12; h++) lg[h] += zv * wpb[d * 12 + h];
            }
        }
    }

    // transposed K / KP reads: lane j reads column j -> coalesced across lanes
    const bf16* kt  = k   + (size_t)b * 98304 + j;
    const bf16* kpt = kpg + (size_t)b * 73728 + j;
    #pragma unroll 2
    for (int h = 0; h < 12; h++) {
        float nd = 0.f;
        #pragma unroll
        for (int d = 0; d < 32; d++)
            nd += qi[h * 32 + d] * b2f(kt[(size_t)(h * 32 + d) * 256]);
        float qk = 0.f, kp2h = 0.f, qp2h = 0.f;
        #pragma unroll
        for (int m = 0; m < 24; m++) {
            float qv = qpi[h * 24 + m], kv = b2f(kpt[(size_t)(h * 24 + m) * 256]);
            qk += qv * kv; kp2h += kv * kv; qp2h += qv * qv;
        }
        float sp = chv[h] * (qp2h + kp2h - 2.f * qk);
        lg[h] = (lg[h] + nd * 0.17677669529663687f + sp) * 0.5773502691896258f;
    }

    int w = tid >> 6;
    #pragma unroll
    for (int h = 0; h < 12; h++) {
        float vv = lg[h];
        for (int off = 32; off; off >>= 1) vv = fmaxf(vv, __shfl_xor(vv, off, 64));
        if ((tid & 63) == 0) red[h][w] = vv;
    }
    __syncthreads();
    float mh[12];
    #pragma unroll
    for (int h = 0; h < 12; h++)
        mh[h] = fmaxf(fmaxf(red[h][0], red[h][1]), fmaxf(red[h][2], red[h][3]));
    #pragma unroll
    for (int h = 0; h < 12; h++) {
        float e = expf(lg[h] - mh[h]); lg[h] = e;
        float ss = e;
        for (int off = 32; off; off >>= 1) ss += __shfl_xor(ss, off, 64);
        if ((tid & 63) == 0) red[h][4 + w] = ss;
    }
    __syncthreads();
    #pragma unroll
    for (int h = 0; h < 12; h++) {
        float S = red[h][4] + red[h][5] + red[h][6] + red[h][7];
        al[h][j] = lg[h] / S;
    }
    __syncthreads();

    for (int o = tid; o < 1440; o += 256) {
        float acc = 0.f;
        if (o < 384) {
            int h = o >> 5;
            const bf16* vb = v + (size_t)b * 256 * 384 + o;
            for (int jj = 0; jj < 256; jj++) acc += al[h][jj] * b2f(vb[(size_t)jj * 384]);
            fr[o] = acc;
        } else if (o < 1152) {
            int oo = o - 384; int h = oo >> 6, d = oo & 63;
            const T* zc = z + (size_t)row * 16384 + d;   // lane-coalesced over d
            for (int jj = 0; jj < 256; jj++) acc += al[h][jj] * LD(zc, (size_t)jj * 64);
            fr[o] = acc;
        } else {
            int o3 = o - 1152; int h = o3 / 24;
            const bf16* vpb = vpg + (size_t)b * 256 * 288 + o3;
            for (int jj = 0; jj < 256; jj++) acc += al[h][jj] * b2f(vpb[(size_t)jj * 288]);
            qpi[o3] = acc;
        }
    }
    __syncthreads();

    if (tid < 96) {
        int t3 = tid * 3;
        float u0 = qpi[t3 + 0] - tv[0], u1 = qpi[t3 + 1] - tv[1], u2 = qpi[t3 + 2] - tv[2];
        float f0 = Rm[0] * u0 + Rm[3] * u1 + Rm[6] * u2;
        float f1 = Rm[1] * u0 + Rm[4] * u1 + Rm[7] * u2;
        float f2 = Rm[2] * u0 + Rm[5] * u1 + Rm[8] * u2;
        float fd = sqrtf(f0 * f0 + f1 * f1 + f2 * f2);
        float inv = 1.f / (fd + 1e-4f);
        fr[1152 + t3 + 0] = f0; fr[1152 + t3 + 1] = f1; fr[1152 + t3 + 2] = f2;
        fr[1440 + tid] = fd;
        fr[1536 + t3 + 0] = f0 * inv; fr[1536 + t3 + 1] = f1 * inv; fr[1536 + t3 + 2] = f2 * inv;
    }
    __syncthreads();

    float* pacc = fsm;
    float* shx  = fsm + 256;
    int col = tid & 127, half = tid >> 7;

    float acc = 0.f;
    #pragma unroll 8
    for (int kk = half * 912; kk < half * 912 + 912; kk++)
        acc += fr[kk] * LD(Wo, oWo + (size_t)kk * 128 + col);
    pacc[tid] = acc;
    __syncthreads();

    auto bsum = [&](float vv) -> float {
        for (int off = 32; off; off >>= 1) vv += __shfl_xor(vv, off, 64);
        if ((tid & 63) == 0) red2[tid >> 6] = vv;
        __syncthreads();
        float s = red2[0] + red2[1] + red2[2] + red2[3];
        __syncthreads();
        return s;
    };

    float val = x[(size_t)row * 128 + col] + LD(bo, oB + col) + pacc[col] + pacc[128 + col];

    float mean = bsum(val) * (1.f / 256.f);
    float dv = val - mean;
    float var = bsum(dv * dv) * (1.f / 256.f);
    float xl = dv * rsqrtf(var + 1e-5f) * LD(g1, oB + col) + LD(b1ln, oB + col);
    shx[col] = xl;
    __syncthreads();

    float a1 = LD(bb1, oB + col);
    #pragma unroll 8
    for (int kk = 0; kk < 128; kk++) a1 += shx[kk] * LD(w1, oM + kk * 128 + col);
    a1 = fmaxf(a1, 0.f);
    __syncthreads();
    shx[col] = a1;
    __syncthreads();

    float a2 = LD(bb2, oB + col);
    #pragma unroll 8
    for (int kk = 0; kk < 128; kk++) a2 += shx[kk] * LD(w2, oM + kk * 128 + col);
    a2 = fmaxf(a2, 0.f);
    __syncthreads();
    shx[col] = a2;
    __syncthreads();

    float a3 = LD(bb3, oB + col);
    #pragma unroll 8
    for (int kk = 0; kk < 128; kk++) a3 += shx[kk] * LD(w3, oM + kk * 128 + col);
    float val2 = xl + a3;

    float mean2 = bsum(val2) * (1.f / 256.f);
    float dv2 = val2 - mean2;
    float var2 = bsum(dv2 * dv2) * (1.f / 256.f);
    if (tid < 128)
        x[(size_t)row * 128 + col] = dv2 * rsqrtf(var2 + 1e-5f) * LD(g2, oB + col) + LD(b2ln, oB + col);
}

__global__ __launch_bounds__(256, 6) void k_attn_post(
    const bf16* q, const bf16* k, const bf16* v,
    const bf16* qpg, const bf16* kpg, const bf16* vpg,
    const void* z, const void* Wpb, const void* coef, const void* rot, const void* pos,
    float* x,
    const void* Wo, const void* bo, const void* g1, const void* b1ln,
    const void* w1, const void* bb1, const void* w2, const void* bb2,
    const void* w3, const void* bb3, const void* g2, const void* b2ln,
    const int* __restrict__ flag, int l)
{
    extern __shared__ char smc[];
    int row = blockIdx.x, tid = threadIdx.x;
    if (*flag) attn_body<bf16>(row, tid, l, smc, q, k, v, qpg, kpg, vpg,
        (const bf16*)z, (const bf16*)Wpb, (const bf16*)coef, (const bf16*)rot, (const bf16*)pos, x,
        (const bf16*)Wo, (const bf16*)bo, (const bf16*)g1, (const bf16*)b1ln,
        (const bf16*)w1, (const bf16*)bb1, (const bf16*)w2, (const bf16*)bb2,
        (const bf16*)w3, (const bf16*)bb3, (const bf16*)g2, (const bf16*)b2ln);
    else attn_body<float>(row, tid, l, smc, q, k, v, qpg, kpg, vpg,
        (const float*)z, (const float*)Wpb, (const float*)coef, (const float*)rot, (const float*)pos, x,
        (const float*)Wo, (const float*)bo, (const float*)g1, (const float*)b1ln,
        (const float*)w1, (const float*)bb1, (const float*)w2, (const float*)bb2,
        (const float*)w3, (const float*)bb3, (const float*)g2, (const float*)b2ln);
}

// ---------- regression head ----------
__global__ void k_final(const float* __restrict__ x, const void* Wreg, const void* breg,
                        void* out, const int* __restrict__ flag)
{
    int idx = blockIdx.x * 256 + threadIdx.x;
    int isBF = *flag;
    int b = idx >> 7, r = (idx >> 2) & 31, c = idx & 3;
    const float* xr = x + ((size_t)(b * 256 + 224 + r)) * 128;
    if (isBF) {
        const bf16* W = (const bf16*)Wreg;
        float acc = b2f(((const bf16*)breg)[c]);
        for (int kk = 0; kk < 128; kk++) acc += xr[kk] * b2f(W[kk * 4 + c]);
        ((bf16*)out)[idx] = f2b(acc);
    } else {
        const float* W = (const float*)Wreg;
        float acc = ((const float*)breg)[c];
        for (int kk = 0; kk < 128; kk++) acc += xr[kk] * W[kk * 4 + c];
        ((float*)out)[idx] = acc;
    }
}

extern "C" void kernel_launch(void* const* d_in, const int* in_sizes, int n_in,
                              void* d_out, int out_size, void* d_ws, size_t ws_size,
                              hipStream_t stream)
{
    const void* rot  = d_in[0];
    const void* pos  = d_in[1];
    const void* resf = d_in[2];
    const void* pair = d_in[3];
    const void* Wq   = d_in[5];
    const void* Wk   = d_in[6];
    const void* Wv   = d_in[7];
    const void* Wpb  = d_in[8];
    const void* coef = d_in[9];
    const void* Wqp  = d_in[10];
    const void* Wkp  = d_in[11];
    const void* Wvp  = d_in[12];
    const void* Wo   = d_in[13];
    const void* bo   = d_in[14];
    const void* ln1g = d_in[15];
    const void* ln1b = d_in[16];
    const void* w1   = d_in[17];
    const void* b1   = d_in[18];
    const void* w2   = d_in[19];
    const void* b2   = d_in[20];
    const void* w3   = d_in[21];
    const void* b3   = d_in[22];
    const void* ln2g = d_in[23];
    const void* ln2b = d_in[24];
    const void* Wreg = d_in[25];
    const void* breg = d_in[26];

    int*   flag = (int*)d_ws;
    float* X    = (float*)d_ws + 16;
    bf16*  Qb   = (bf16*)(X + (size_t)BL * 128);
    bf16*  Kb   = Qb   + (size_t)BL * QH;
    bf16*  Vb   = Kb   + (size_t)BL * QH;
    bf16*  QPGb = Vb   + (size_t)BL * QH;
    bf16*  KPGb = QPGb + (size_t)BL * PH;
    bf16*  VPGb = KPGb + (size_t)BL * PH;

    const size_t SM_PROJ = 2156 * sizeof(float);
    const size_t SM_ATTN = 6460 * sizeof(float);   // 25840 B

    k_sniff<<<1, 64, 0, stream>>>(rot, flag);
    k_init<<<BL * 128 / 256, 256, 0, stream>>>(resf, X, flag);

    for (int l = 0; l < 6; l++) {
        k_proj<<<BL, 256, SM_PROJ, stream>>>(
            X, Wq, Wk, Wv, Wqp, Wkp, Wvp, rot, pos,
            Qb, Kb, Vb, QPGb, KPGb, VPGb, flag, l);
        k_attn_post<<<BL, 256, SM_ATTN, stream>>>(
            Qb, Kb, Vb, QPGb, KPGb, VPGb,
            pair, Wpb, coef, rot, pos, X,
            Wo, bo, ln1g, ln1b, w1, b1, w2, b2, w3, b3, ln2g, ln2b, flag, l);
    }

    k_final<<<4, 256, 0, stream>>>(X, Wreg, breg, d_out, flag);
}